// Round 2
// baseline (1019204.297 us; speedup 1.0000x reference)
//
#include <hip/hip_runtime.h>
#include <math.h>

#define NN 4096      // points
#define NC 768       // feature dim
#define KK 16        // knn k
#define SK 128       // spectral basis size
#define LM 1024      // Lanczos steps
#define LAMBDA_ 100.0f

typedef unsigned int u32;

__device__ __forceinline__ float hashf(u32 x) {
  x ^= x >> 16; x *= 0x7feb352dU; x ^= x >> 15; x *= 0x846ca68bU; x ^= x >> 16;
  return ((float)x) * (1.0f / 4294967296.0f);  // [0,1)
}

// ---------- row squared norms ----------
__global__ void k_sqnorm(const float* __restrict__ f, float* __restrict__ sq) {
  __shared__ float red[256];
  int i = blockIdx.x;
  float s = 0.f;
  for (int c = threadIdx.x; c < NC; c += 256) { float v = f[(size_t)i * NC + c]; s += v * v; }
  red[threadIdx.x] = s; __syncthreads();
  for (int o = 128; o > 0; o >>= 1) { if (threadIdx.x < o) red[threadIdx.x] += red[threadIdx.x + o]; __syncthreads(); }
  if (threadIdx.x == 0) sq[i] = red[0];
}

// ---------- d2 panel: pan[256][NN] for rows i0..i0+255 ----------
__global__ void __launch_bounds__(256) k_d2panel(const float* __restrict__ f, const float* __restrict__ sq,
                                                 float* __restrict__ pan, int i0) {
  __shared__ float As[16][65], Bs[16][65];
  int bj = blockIdx.x, bi = blockIdx.y;
  int row0 = i0 + bi * 64, col0 = bj * 64;
  int tx = threadIdx.x & 15, ty = threadIdx.x >> 4;
  float acc[4][4] = {};
  for (int k0 = 0; k0 < NC; k0 += 16) {
    for (int t2 = threadIdx.x; t2 < 1024; t2 += 256) {
      int kk = t2 & 15, rr = t2 >> 4;
      As[kk][rr] = f[(size_t)(row0 + rr) * NC + k0 + kk];
      Bs[kk][rr] = f[(size_t)(col0 + rr) * NC + k0 + kk];
    }
    __syncthreads();
#pragma unroll
    for (int kk = 0; kk < 16; kk++) {
      float av[4], bv[4];
#pragma unroll
      for (int a = 0; a < 4; a++) av[a] = As[kk][ty * 4 + a];
#pragma unroll
      for (int b = 0; b < 4; b++) bv[b] = Bs[kk][tx * 4 + b];
#pragma unroll
      for (int a = 0; a < 4; a++)
#pragma unroll
        for (int b = 0; b < 4; b++) acc[a][b] += av[a] * bv[b];
    }
    __syncthreads();
  }
#pragma unroll
  for (int a = 0; a < 4; a++) {
    int gr = row0 + ty * 4 + a;
    int pr = bi * 64 + ty * 4 + a;
    float sr = sq[gr];
#pragma unroll
    for (int b = 0; b < 4; b++) {
      int gc = col0 + tx * 4 + b;
      float v = sr + sq[gc] - 2.f * acc[a][b];
      v = fmaxf(v, 0.f);
      if (gr == gc) v += 1e10f;
      pan[(size_t)pr * NN + gc] = v;
    }
  }
}

// ---------- top-16 smallest per row ----------
__global__ void __launch_bounds__(256) k_topk(const float* __restrict__ pan, int i0,
                                              int* __restrict__ idx, float* __restrict__ dkv) {
  __shared__ float vals[NN];
  __shared__ float rv[256];
  __shared__ int ri[256];
  int r = blockIdx.x;
  const float* row = pan + (size_t)r * NN;
  for (int j = threadIdx.x; j < NN; j += 256) vals[j] = row[j];
  __syncthreads();
  for (int t3 = 0; t3 < KK; t3++) {
    float bv = 1e30f; int bi2 = NN;
    for (int j2 = threadIdx.x; j2 < NN; j2 += 256) {
      float v = vals[j2];
      if (v < bv || (v == bv && j2 < bi2)) { bv = v; bi2 = j2; }
    }
    rv[threadIdx.x] = bv; ri[threadIdx.x] = bi2;
    __syncthreads();
    for (int o = 128; o > 0; o >>= 1) {
      if (threadIdx.x < o) {
        float v2 = rv[threadIdx.x + o]; int i2 = ri[threadIdx.x + o];
        if (v2 < rv[threadIdx.x] || (v2 == rv[threadIdx.x] && i2 < ri[threadIdx.x])) {
          rv[threadIdx.x] = v2; ri[threadIdx.x] = i2;
        }
      }
      __syncthreads();
    }
    if (threadIdx.x == 0) {
      idx[(size_t)(i0 + r) * KK + t3] = ri[0];
      dkv[(size_t)(i0 + r) * KK + t3] = rv[0];
      vals[ri[0]] = 1e30f;
    }
    __syncthreads();
  }
}

// ---------- sigma2 = mean(dkv) + 1e-12 ----------
__global__ void k_partsum(const float* __restrict__ dkv, double* __restrict__ part) {
  __shared__ double red[256];
  double s = 0.0;
  for (int t2 = blockIdx.x * 256 + threadIdx.x; t2 < NN * KK; t2 += 64 * 256) s += (double)dkv[t2];
  red[threadIdx.x] = s; __syncthreads();
  for (int o = 128; o > 0; o >>= 1) { if (threadIdx.x < o) red[threadIdx.x] += red[threadIdx.x + o]; __syncthreads(); }
  if (threadIdx.x == 0) part[blockIdx.x] = red[0];
}
__global__ void k_sigma(const double* __restrict__ part, double* __restrict__ scal) {
  __shared__ double red[64];
  red[threadIdx.x] = part[threadIdx.x]; __syncthreads();
  for (int o = 32; o > 0; o >>= 1) { if (threadIdx.x < o) red[threadIdx.x] += red[threadIdx.x + o]; __syncthreads(); }
  if (threadIdx.x == 0) scal[0] = red[0] / (double)(NN * KK) + 1e-12;
}

// ---------- gaussian weights (no atomics) ----------
__global__ void k_wexp(const float* __restrict__ dkv, const double* __restrict__ scal,
                       float* __restrict__ wv) {
  int t = blockIdx.x * 256 + threadIdx.x;
  if (t >= NN * KK) return;
  float inv2s = (float)(0.5 / scal[0]);
  wv[t] = expf(-dkv[t] * inv2s);
}

// ---------- deterministic CSR transpose construction ----------
__global__ void k_count(const int* __restrict__ idx, int* __restrict__ cnt) {
  int t = blockIdx.x * 256 + threadIdx.x;
  if (t < NN * KK) atomicAdd(&cnt[idx[t]], 1);  // int atomics: order-invariant result
}

__global__ void __launch_bounds__(1024) k_scan(const int* __restrict__ cnt,
                                               int* __restrict__ roff, int* __restrict__ rpos) {
  __shared__ int buf[1024];
  int t = threadIdx.x;
  int v[4]; int s = 0;
#pragma unroll
  for (int u = 0; u < 4; u++) { v[u] = cnt[t * 4 + u]; s += v[u]; }
  buf[t] = s; __syncthreads();
  for (int o = 1; o < 1024; o <<= 1) {
    int x = (t >= o) ? buf[t - o] : 0;
    __syncthreads();
    buf[t] += x;
    __syncthreads();
  }
  int run = (t == 0) ? 0 : buf[t - 1];
#pragma unroll
  for (int u = 0; u < 4; u++) { roff[t * 4 + u] = run; rpos[t * 4 + u] = run; run += v[u]; }
  if (t == 1023) roff[NN] = run;
}

__global__ void k_place(const int* __restrict__ idx, int* __restrict__ rpos, int* __restrict__ tsrc) {
  int i = blockIdx.x * 256 + threadIdx.x;
  if (i >= NN) return;
  for (int l = 0; l < KK; l++) {
    int j = idx[(size_t)i * KK + l];
    int e = atomicAdd(&rpos[j], 1);            // ticket; order fixed by sort below
    tsrc[e] = i * KK + l;
  }
}

__global__ void k_sortb(const int* __restrict__ roff, int* __restrict__ tsrc) {
  int i = blockIdx.x * 256 + threadIdx.x;
  if (i >= NN) return;
  int b = roff[i], e = roff[i + 1];
  for (int a = b + 1; a < e; a++) {            // insertion sort -> canonical edge order
    int key = tsrc[a]; int c = a - 1;
    while (c >= b && tsrc[c] > key) { tsrc[c + 1] = tsrc[c]; c--; }
    tsrc[c + 1] = key;
  }
}

// ---------- degrees (deterministic, gather-only) ----------
__global__ void k_deg(const float* __restrict__ wv, const int* __restrict__ roff,
                      const int* __restrict__ tsrc, float* __restrict__ deg) {
  int i = blockIdx.x * 256 + threadIdx.x;
  if (i >= NN) return;
  float s = 0.f;
  for (int l = 0; l < KK; l++) s += wv[(size_t)i * KK + l];
  float s2 = 0.f;
  for (int e = roff[i]; e < roff[i + 1]; e++) s2 += wv[tsrc[e]];
  deg[i] = 0.5f * (s + s2);
}

// ---------- normalized adjacency: row part + transpose part ----------
__global__ void k_wadj2(const float* __restrict__ wv, const int* __restrict__ idx,
                        const int* __restrict__ roff, const int* __restrict__ tsrc,
                        const float* __restrict__ deg,
                        float* __restrict__ wadjr, float* __restrict__ wadjt,
                        int* __restrict__ tcol) {
  int i = blockIdx.x * 256 + threadIdx.x;
  if (i >= NN) return;
  float di = 1.0f / sqrtf(deg[i] + 1e-8f);
  for (int l = 0; l < KK; l++) {
    int j = idx[(size_t)i * KK + l];
    float dj = 1.0f / sqrtf(deg[j] + 1e-8f);
    wadjr[(size_t)i * KK + l] = 0.5f * wv[(size_t)i * KK + l] * di * dj;
  }
  for (int e = roff[i]; e < roff[i + 1]; e++) {
    int s = tsrc[e];
    int sn = s / KK;
    float dj = 1.0f / sqrtf(deg[sn] + 1e-8f);
    wadjt[e] = 0.5f * wv[s] * di * dj;
    tcol[e] = sn;
  }
}

// ---------- init Lanczos residual ----------
__global__ void k_qinit(float* __restrict__ y, u32 seed) {
  int n = blockIdx.x * 256 + threadIdx.x;
  if (n < NN) y[n] = hashf((u32)n * 2246822519u + seed) - 0.5f;
}

// ---------- Lanczos step A: normalize y -> q_it, then y = M q_it (pure gather) ----------
__global__ void __launch_bounds__(1024) k_lanc_a(float* __restrict__ Q, float* __restrict__ y,
                                                 const float* __restrict__ wadjr, const int* __restrict__ idx,
                                                 const float* __restrict__ wadjt, const int* __restrict__ tcol,
                                                 const int* __restrict__ roff,
                                                 double* __restrict__ Tb, int it) {
  __shared__ double red[1024];
  int t = threadIdx.x;
  double s = 0.0;
  for (int n = t; n < NN; n += 1024) { double v = (double)y[n]; s += v * v; }
  red[t] = s; __syncthreads();
  for (int o = 512; o > 0; o >>= 1) { if (t < o) red[t] += red[t + o]; __syncthreads(); }
  double nrm = sqrt(red[0]);
  if (t == 0 && it > 0) Tb[it - 1] = nrm;
  float inv = (float)(1.0 / (nrm > 1e-300 ? nrm : 1e-300));
  float* q = Q + (size_t)it * NN;
  for (int n = t; n < NN; n += 1024) q[n] = y[n] * inv;
  __syncthreads();
  for (int n = t; n < NN; n += 1024) {
    float acc = 0.f;
#pragma unroll
    for (int l = 0; l < KK; l++) acc += wadjr[(size_t)n * KK + l] * q[idx[(size_t)n * KK + l]];
    for (int e = roff[n]; e < roff[n + 1]; e++) acc += wadjt[e] * q[tcol[e]];
    y[n] = acc;
  }
}

// ---------- dots c[j] = q_j . y ----------
__global__ void k_dots(const float* __restrict__ Q, const float* __restrict__ y,
                       float* __restrict__ c, double* __restrict__ Ta, int it, int storeA) {
  __shared__ double red[256];
  int j = blockIdx.x;
  const float* q = Q + (size_t)j * NN;
  double s = 0.0;
  for (int n = threadIdx.x; n < NN; n += 256) s += (double)q[n] * (double)y[n];
  red[threadIdx.x] = s; __syncthreads();
  for (int o = 128; o > 0; o >>= 1) { if (threadIdx.x < o) red[threadIdx.x] += red[threadIdx.x + o]; __syncthreads(); }
  if (threadIdx.x == 0) { c[j] = (float)red[0]; if (storeA && j == it) Ta[it] = red[0]; }
}

// ---------- y -= Q[0..it]^T c ----------
__global__ void k_upd(const float* __restrict__ Q, const float* __restrict__ c,
                      float* __restrict__ y, int it) {
  int n = blockIdx.x * 256 + threadIdx.x;
  float s = y[n];
  for (int j = 0; j <= it; j++) s -= Q[(size_t)j * NN + n] * c[j];
  y[n] = s;
}

// ---------- bisection: top-SK eigenvalues of T (descending) ----------
__global__ void k_bisect(const double* __restrict__ Ta, const double* __restrict__ Tb,
                         double* __restrict__ theta, float* __restrict__ evL) {
  int j = threadIdx.x;
  if (j >= SK) return;
  int tgt = LM - j;  // tgt-th smallest (1-indexed) = j-th largest
  double lo = -2.0, hi = 2.0;
  for (int iter = 0; iter < 60; iter++) {
    double mid = 0.5 * (lo + hi);
    int cnt = 0; double q = 1.0;
    for (int k = 0; k < LM; k++) {
      double off = (k > 0) ? Tb[k - 1] * Tb[k - 1] : 0.0;
      q = Ta[k] - mid - off / q;
      if (q < 0.0) cnt++;
      if (fabs(q) < 1e-280) q = -1e-280;
    }
    if (cnt >= tgt) hi = mid; else lo = mid;
  }
  theta[j] = 0.5 * (lo + hi);
  evL[j] = (float)(1.0 - theta[j]);  // ascending eigenvalues of L
}

// ---------- inverse iteration for eigenvectors of T ----------
__global__ void k_invit(const double* __restrict__ Ta, const double* __restrict__ Tb,
                        const double* __restrict__ theta,
                        double* __restrict__ dws, double* __restrict__ ews,
                        double* __restrict__ fws, double* __restrict__ rws,
                        float* __restrict__ Ym) {
  int j = threadIdx.x;
  if (j >= SK) return;
  double sig = theta[j];
  for (int k = 0; k < LM; k++)
    rws[(size_t)k * SK + j] = (double)hashf((u32)k * 2654435761u + (u32)j * 40503u + 17u) - 0.5;
  for (int pass = 0; pass < 3; pass++) {
    double dk = Ta[0] - sig;
    double ek = Tb[0];
    double fk = 0.0;
    double rk = rws[j];
    for (int k = 0; k < LM - 1; k++) {
      double bk = Tb[k];
      double dn = Ta[k + 1] - sig;
      double en = (k + 2 < LM) ? Tb[k + 1] : 0.0;
      double rn = rws[(size_t)(k + 1) * SK + j];
      double dd, ee, ff, dk2, ek2, rkeep, rnext;
      if (fabs(dk) >= fabs(bk)) {
        double dsafe = (fabs(dk) > 1e-300) ? dk : 1e-300;
        double m = bk / dsafe;
        dd = dsafe; ee = ek; ff = fk;
        dk2 = dn - m * ek;
        ek2 = en - m * fk;
        rkeep = rk;
        rnext = rn - m * rk;
      } else {
        double m = dk / bk;
        dd = bk; ee = dn; ff = en;
        dk2 = ek - m * dn;
        ek2 = fk - m * en;
        rkeep = rn;
        rnext = rk - m * rn;
      }
      dws[(size_t)k * SK + j] = dd;
      ews[(size_t)k * SK + j] = ee;
      fws[(size_t)k * SK + j] = ff;
      rws[(size_t)k * SK + j] = rkeep;
      rk = rnext; dk = dk2; ek = ek2; fk = 0.0;
    }
    if (fabs(dk) < 1e-300) dk = 1e-300;
    dws[(size_t)(LM - 1) * SK + j] = dk;
    ews[(size_t)(LM - 1) * SK + j] = 0.0;
    fws[(size_t)(LM - 1) * SK + j] = 0.0;
    rws[(size_t)(LM - 1) * SK + j] = rk;
    double y1 = 0.0, y2 = 0.0, nr = 0.0;
    for (int k = LM - 1; k >= 0; k--) {
      double dv = dws[(size_t)k * SK + j];
      double yk = (rws[(size_t)k * SK + j] - ews[(size_t)k * SK + j] * y1 - fws[(size_t)k * SK + j] * y2) / dv;
      rws[(size_t)k * SK + j] = yk;
      y2 = y1; y1 = yk;
      nr += yk * yk;
    }
    double inv = 1.0 / sqrt(nr > 1e-300 ? nr : 1e-300);
    for (int k = 0; k < LM; k++) rws[(size_t)k * SK + j] *= inv;
  }
  for (int k = 0; k < LM; k++) Ym[(size_t)k * SK + j] = (float)rws[(size_t)k * SK + j];
}

// ---------- MGS on Ym columns ----------
__device__ __forceinline__ double wred64(double v) {
  for (int o = 32; o > 0; o >>= 1) v += __shfl_down(v, o, 64);
  return v;
}
__global__ void __launch_bounds__(256) k_mgsY(float* __restrict__ Ym) {
  __shared__ double lds[8];
  int t = threadIdx.x;
  for (int j = 0; j < SK; j++) {
    for (int jj = 0; jj < j; jj++) {
      double s = 0.0;
      for (int k = t; k < LM; k += 256) s += (double)Ym[(size_t)k * SK + jj] * (double)Ym[(size_t)k * SK + j];
      __syncthreads();
      s = wred64(s);
      if ((t & 63) == 0) lds[t >> 6] = s;
      __syncthreads();
      float cf = (float)(lds[0] + lds[1] + lds[2] + lds[3]);
      for (int k = t; k < LM; k += 256) Ym[(size_t)k * SK + j] -= cf * Ym[(size_t)k * SK + jj];
    }
    double s = 0.0;
    __syncthreads();
    for (int k = t; k < LM; k += 256) { double v = (double)Ym[(size_t)k * SK + j]; s += v * v; }
    s = wred64(s);
    if ((t & 63) == 0) lds[t >> 6] = s;
    __syncthreads();
    double nr = lds[0] + lds[1] + lds[2] + lds[3];
    float inv = (float)(1.0 / sqrt(nr > 1e-300 ? nr : 1e-300));
    for (int k = t; k < LM; k += 256) Ym[(size_t)k * SK + j] *= inv;
    __syncthreads();
  }
}

// ---------- generic tiled GEMMs ----------
__global__ void __launch_bounds__(256) k_gemm_tn(const float* __restrict__ A, const float* __restrict__ B,
                                                 float* __restrict__ Cm, int M, int P, int Kd) {
  __shared__ float As[16][65], Bs[16][65];
  int bm = blockIdx.x * 64, bp = blockIdx.y * 64;
  int tx = threadIdx.x & 15, ty = threadIdx.x >> 4;
  float acc[4][4] = {};
  for (int k0 = 0; k0 < Kd; k0 += 16) {
    for (int t2 = threadIdx.x; t2 < 1024; t2 += 256) {
      int mm = t2 & 63, kk = t2 >> 6;
      As[kk][mm] = A[(size_t)(k0 + kk) * M + bm + mm];
      Bs[kk][mm] = B[(size_t)(k0 + kk) * P + bp + mm];
    }
    __syncthreads();
#pragma unroll
    for (int kk = 0; kk < 16; kk++) {
      float av[4], bv[4];
#pragma unroll
      for (int a = 0; a < 4; a++) av[a] = As[kk][ty * 4 + a];
#pragma unroll
      for (int b = 0; b < 4; b++) bv[b] = Bs[kk][tx * 4 + b];
#pragma unroll
      for (int a = 0; a < 4; a++)
#pragma unroll
        for (int b = 0; b < 4; b++) acc[a][b] += av[a] * bv[b];
    }
    __syncthreads();
  }
#pragma unroll
  for (int a = 0; a < 4; a++)
#pragma unroll
    for (int b = 0; b < 4; b++)
      Cm[(size_t)(bm + ty * 4 + a) * P + bp + tx * 4 + b] = acc[a][b];
}

__global__ void __launch_bounds__(256) k_gemm_nt(const float* __restrict__ A, const float* __restrict__ B,
                                                 float* __restrict__ Cm, int M, int P, int Kd) {
  __shared__ float As[16][65], Bs[16][65];
  int bm = blockIdx.x * 64, bp = blockIdx.y * 64;
  int tx = threadIdx.x & 15, ty = threadIdx.x >> 4;
  float acc[4][4] = {};
  for (int k0 = 0; k0 < Kd; k0 += 16) {
    for (int t2 = threadIdx.x; t2 < 1024; t2 += 256) {
      int kk = t2 & 15, mm = t2 >> 4;
      As[kk][mm] = A[(size_t)(bm + mm) * Kd + k0 + kk];
      Bs[kk][mm] = B[(size_t)(bp + mm) * Kd + k0 + kk];
    }
    __syncthreads();
#pragma unroll
    for (int kk = 0; kk < 16; kk++) {
      float av[4], bv[4];
#pragma unroll
      for (int a = 0; a < 4; a++) av[a] = As[kk][ty * 4 + a];
#pragma unroll
      for (int b = 0; b < 4; b++) bv[b] = Bs[kk][tx * 4 + b];
#pragma unroll
      for (int a = 0; a < 4; a++)
#pragma unroll
        for (int b = 0; b < 4; b++) acc[a][b] += av[a] * bv[b];
    }
    __syncthreads();
  }
#pragma unroll
  for (int a = 0; a < 4; a++)
#pragma unroll
    for (int b = 0; b < 4; b++)
      Cm[(size_t)(bm + ty * 4 + a) * P + bp + tx * 4 + b] = acc[a][b];
}

__global__ void __launch_bounds__(256) k_gemm_nn(const float* __restrict__ A, const float* __restrict__ B,
                                                 float* __restrict__ Cm, int M, int P, int Kd) {
  __shared__ float As[16][65], Bs[16][65];
  int bm = blockIdx.x * 64, bp = blockIdx.y * 64;
  int tx = threadIdx.x & 15, ty = threadIdx.x >> 4;
  float acc[4][4] = {};
  for (int k0 = 0; k0 < Kd; k0 += 16) {
    for (int t2 = threadIdx.x; t2 < 1024; t2 += 256) {
      int kk = t2 & 15, mm = t2 >> 4;
      As[kk][mm] = A[(size_t)(bm + mm) * Kd + k0 + kk];
    }
    for (int t2 = threadIdx.x; t2 < 1024; t2 += 256) {
      int mm = t2 & 63, kk = t2 >> 6;
      Bs[kk][mm] = B[(size_t)(k0 + kk) * P + bp + mm];
    }
    __syncthreads();
#pragma unroll
    for (int kk = 0; kk < 16; kk++) {
      float av[4], bv[4];
#pragma unroll
      for (int a = 0; a < 4; a++) av[a] = As[kk][ty * 4 + a];
#pragma unroll
      for (int b = 0; b < 4; b++) bv[b] = Bs[kk][tx * 4 + b];
#pragma unroll
      for (int a = 0; a < 4; a++)
#pragma unroll
        for (int b = 0; b < 4; b++) acc[a][b] += av[a] * bv[b];
    }
    __syncthreads();
  }
#pragma unroll
  for (int a = 0; a < 4; a++)
#pragma unroll
    for (int b = 0; b < 4; b++)
      Cm[(size_t)(bm + ty * 4 + a) * P + bp + tx * 4 + b] = acc[a][b];
}

// ---------- s = max(max ev_a, max ev_b) ----------
__global__ void k_smax(const float* __restrict__ ea, const float* __restrict__ eb, double* __restrict__ scal) {
  __shared__ float red[128];
  int t = threadIdx.x;
  red[t] = fmaxf(ea[t], eb[t]);
  __syncthreads();
  for (int o = 64; o > 0; o >>= 1) { if (t < o) red[t] = fmaxf(red[t], red[t + o]); __syncthreads(); }
  if (t == 0) scal[1] = (double)red[0];
}

// ---------- resolvent mask ----------
__global__ void k_mask(const float* __restrict__ evr, const float* __restrict__ evc,
                       const double* __restrict__ scal, float* __restrict__ Dm) {
  int t = blockIdx.x * 256 + threadIdx.x;
  if (t >= SK * SK) return;
  int i = t / SK, j = t % SK;
  float s = (float)scal[1];
  float g1 = sqrtf(fmaxf(evc[j] / s, 0.f));
  float g2 = sqrtf(fmaxf(evr[i] / s, 0.f));
  float a2 = g2 * g2 + 1.f, a1 = g1 * g1 + 1.f;
  float re = g2 / a2 - g1 / a1;
  float im = 1.f / a2 - 1.f / a1;
  Dm[t] = re * re + im * im;
}

// ---------- per-row Cholesky solve: (AAt + lam diag(D_i)) x = BAt_i ----------
__global__ void __launch_bounds__(128) k_cholsolve(const float* __restrict__ AAt, const float* __restrict__ BAt,
                                                   const float* __restrict__ Dm, float* __restrict__ Msg,
                                                   float* __restrict__ Cout) {
  __shared__ float xs[SK];
  int i = blockIdx.x;
  float* Ms = Msg + (size_t)i * SK * SK;
  for (int t2 = threadIdx.x; t2 < SK * SK; t2 += 128) {
    int r = t2 / SK, c2 = t2 % SK;
    float v = AAt[t2];
    if (r == c2) v += LAMBDA_ * Dm[(size_t)i * SK + r];
    Ms[t2] = v;
  }
  if (threadIdx.x < SK) xs[threadIdx.x] = BAt[(size_t)i * SK + threadIdx.x];
  __syncthreads();
  for (int k = 0; k < SK; k++) {
    if (threadIdx.x == 0) Ms[k * SK + k] = sqrtf(fmaxf(Ms[k * SK + k], 1e-20f));
    __syncthreads();
    float dk = Ms[k * SK + k];
    for (int r = k + 1 + threadIdx.x; r < SK; r += 128) Ms[r * SK + k] /= dk;
    __syncthreads();
    int rem = SK - k - 1;
    for (int t2 = threadIdx.x; t2 < rem * rem; t2 += 128) {
      int r = k + 1 + t2 / rem, c2 = k + 1 + t2 % rem;
      Ms[r * SK + c2] -= Ms[r * SK + k] * Ms[c2 * SK + k];
    }
    __syncthreads();
  }
  for (int k = 0; k < SK; k++) {
    if (threadIdx.x == 0) xs[k] /= Ms[k * SK + k];
    __syncthreads();
    float xv = xs[k];
    for (int r = k + 1 + threadIdx.x; r < SK; r += 128) xs[r] -= Ms[r * SK + k] * xv;
    __syncthreads();
  }
  for (int k = SK - 1; k >= 0; k--) {
    if (threadIdx.x == 0) xs[k] /= Ms[k * SK + k];
    __syncthreads();
    float xv = xs[k];
    for (int r = threadIdx.x; r < k; r += 128) xs[r] -= Ms[k * SK + r] * xv;
    __syncthreads();
  }
  for (int t2 = threadIdx.x; t2 < SK; t2 += 128) Cout[(size_t)i * SK + t2] = xs[t2];
}

// ---------- loss partials (deterministic: per-block slots, no float atomics) ----------
__global__ void k_frob_iden(const float* __restrict__ Mat, double* __restrict__ lpart, int slot) {
  __shared__ double red[256];
  double s = 0.0;
  for (int t2 = blockIdx.x * 256 + threadIdx.x; t2 < SK * SK; t2 += 32 * 256) {
    float v = Mat[t2] - ((t2 / SK == t2 % SK) ? 1.f : 0.f);
    s += (double)v * (double)v;
  }
  red[threadIdx.x] = s; __syncthreads();
  for (int o = 128; o > 0; o >>= 1) { if (threadIdx.x < o) red[threadIdx.x] += red[threadIdx.x + o]; __syncthreads(); }
  if (threadIdx.x == 0) lpart[slot * 32 + blockIdx.x] = red[0];
}
__global__ void k_lap(const float* __restrict__ Cm, const float* __restrict__ evc,
                      const float* __restrict__ evr, double* __restrict__ lpart, int slot) {
  __shared__ double red[256];
  double s = 0.0;
  for (int t2 = blockIdx.x * 256 + threadIdx.x; t2 < SK * SK; t2 += 32 * 256) {
    int i = t2 / SK, j = t2 % SK;
    float v = Cm[t2] * (evc[j] - evr[i]);
    s += (double)v * (double)v;
  }
  red[threadIdx.x] = s; __syncthreads();
  for (int o = 128; o > 0; o >>= 1) { if (threadIdx.x < o) red[threadIdx.x] += red[threadIdx.x + o]; __syncthreads(); }
  if (threadIdx.x == 0) lpart[slot * 32 + blockIdx.x] = red[0];
}
__global__ void k_writeout(const double* __restrict__ lpart, float* __restrict__ out) {
  if (threadIdx.x == 0) {
    double b = 0.0, o = 0.0, l = 0.0;
    for (int s = 0; s < 64; s++) b += lpart[s];         // slots 0,1: l_bij
    for (int s = 64; s < 128; s++) o += lpart[s];       // slots 2,3: l_orth
    for (int s = 128; s < 192; s++) l += lpart[s];      // slots 4,5: l_lap
    out[0] = (float)b; out[1] = (float)o; out[2] = (float)l;
  }
}

extern "C" void kernel_launch(void* const* d_in, const int* in_sizes, int n_in,
                              void* d_out, int out_size, void* d_ws, size_t ws_size,
                              hipStream_t stream) {
  const float* feats[2] = {(const float*)d_in[0], (const float*)d_in[1]};
  char* p = (char*)d_ws;
  auto alloc = [&](size_t bytes) -> void* {
    char* r = p;
    p += (bytes + 255) & ~(size_t)255;
    return (void*)r;
  };
  float* pan   = (float*)alloc(sizeof(float) * 256 * NN);
  float* sq    = (float*)alloc(sizeof(float) * NN);
  int*   idx   = (int*)alloc(sizeof(int) * (size_t)NN * KK);
  float* dkv   = (float*)alloc(sizeof(float) * (size_t)NN * KK);
  float* wv    = (float*)alloc(sizeof(float) * (size_t)NN * KK);
  float* wadjr = (float*)alloc(sizeof(float) * (size_t)NN * KK);
  float* wadjt = (float*)alloc(sizeof(float) * (size_t)NN * KK);
  int*   cnt   = (int*)alloc(sizeof(int) * NN);
  int*   roff  = (int*)alloc(sizeof(int) * (NN + 1));
  int*   rpos  = (int*)alloc(sizeof(int) * NN);
  int*   tsrc  = (int*)alloc(sizeof(int) * (size_t)NN * KK);
  int*   tcol  = (int*)alloc(sizeof(int) * (size_t)NN * KK);
  float* deg   = (float*)alloc(sizeof(float) * NN);
  float* Q     = (float*)alloc(sizeof(float) * (size_t)LM * NN);
  float* yv    = (float*)alloc(sizeof(float) * NN);
  float* cv    = (float*)alloc(sizeof(float) * LM);
  double* part = (double*)alloc(sizeof(double) * 64);
  double* scal = (double*)alloc(sizeof(double) * 8);
  double* Ta   = (double*)alloc(sizeof(double) * LM);
  double* Tb   = (double*)alloc(sizeof(double) * LM);
  double* theta= (double*)alloc(sizeof(double) * SK);
  double* dws  = (double*)alloc(sizeof(double) * (size_t)LM * SK);
  double* ews  = (double*)alloc(sizeof(double) * (size_t)LM * SK);
  double* fws  = (double*)alloc(sizeof(double) * (size_t)LM * SK);
  double* rws  = (double*)alloc(sizeof(double) * (size_t)LM * SK);
  float* Ym    = (float*)alloc(sizeof(float) * (size_t)LM * SK);
  float* U0    = (float*)alloc(sizeof(float) * (size_t)NN * SK);
  float* U1    = (float*)alloc(sizeof(float) * (size_t)NN * SK);
  float* ev0   = (float*)alloc(sizeof(float) * SK);
  float* ev1   = (float*)alloc(sizeof(float) * SK);
  float* Ac    = (float*)alloc(sizeof(float) * (size_t)SK * NC);
  float* Bc    = (float*)alloc(sizeof(float) * (size_t)SK * NC);
  float* AAt   = (float*)alloc(sizeof(float) * SK * SK);
  float* BAt   = (float*)alloc(sizeof(float) * SK * SK);
  float* Dm    = (float*)alloc(sizeof(float) * SK * SK);
  float* Cxy   = (float*)alloc(sizeof(float) * SK * SK);
  float* Cyx   = (float*)alloc(sizeof(float) * SK * SK);
  float* P1    = (float*)alloc(sizeof(float) * SK * SK);
  float* Msg   = (float*)alloc(sizeof(float) * (size_t)SK * SK * SK);
  double* lpart= (double*)alloc(sizeof(double) * 192);

  float* Us[2] = {U0, U1};
  float* evs[2] = {ev0, ev1};

  for (int s2 = 0; s2 < 2; s2++) {
    const float* f = feats[s2];
    k_sqnorm<<<NN, 256, 0, stream>>>(f, sq);
    for (int p2 = 0; p2 < 16; p2++) {
      k_d2panel<<<dim3(64, 4), 256, 0, stream>>>(f, sq, pan, p2 * 256);
      k_topk<<<256, 256, 0, stream>>>(pan, p2 * 256, idx, dkv);
    }
    k_partsum<<<64, 256, 0, stream>>>(dkv, part);
    k_sigma<<<1, 64, 0, stream>>>(part, scal);
    k_wexp<<<NN * KK / 256, 256, 0, stream>>>(dkv, scal, wv);
    // deterministic CSR transpose
    hipMemsetAsync(cnt, 0, sizeof(int) * NN, stream);
    k_count<<<NN * KK / 256, 256, 0, stream>>>(idx, cnt);
    k_scan<<<1, 1024, 0, stream>>>(cnt, roff, rpos);
    k_place<<<16, 256, 0, stream>>>(idx, rpos, tsrc);
    k_sortb<<<16, 256, 0, stream>>>(roff, tsrc);
    k_deg<<<16, 256, 0, stream>>>(wv, roff, tsrc, deg);
    k_wadj2<<<16, 256, 0, stream>>>(wv, idx, roff, tsrc, deg, wadjr, wadjt, tcol);
    // Lanczos with full CGS2 reorthogonalization
    k_qinit<<<16, 256, 0, stream>>>(yv, 1234567u + (u32)s2 * 77777u);
    for (int it = 0; it < LM; it++) {
      k_lanc_a<<<1, 1024, 0, stream>>>(Q, yv, wadjr, idx, wadjt, tcol, roff, Tb, it);
      k_dots<<<it + 1, 256, 0, stream>>>(Q, yv, cv, Ta, it, 1);
      k_upd<<<16, 256, 0, stream>>>(Q, cv, yv, it);
      k_dots<<<it + 1, 256, 0, stream>>>(Q, yv, cv, Ta, it, 0);
      k_upd<<<16, 256, 0, stream>>>(Q, cv, yv, it);
    }
    k_bisect<<<1, 128, 0, stream>>>(Ta, Tb, theta, evs[s2]);
    k_invit<<<1, 128, 0, stream>>>(Ta, Tb, theta, dws, ews, fws, rws, Ym);
    k_mgsY<<<1, 256, 0, stream>>>(Ym);
    k_gemm_tn<<<dim3(NN / 64, SK / 64), 256, 0, stream>>>(Q, Ym, Us[s2], NN, SK, LM);
  }

  // spectral coefficients
  k_gemm_tn<<<dim3(SK / 64, NC / 64), 256, 0, stream>>>(U0, feats[0], Ac, SK, NC, NN);
  k_gemm_tn<<<dim3(SK / 64, NC / 64), 256, 0, stream>>>(U1, feats[1], Bc, SK, NC, NN);
  k_smax<<<1, 128, 0, stream>>>(ev0, ev1, scal);

  // Cxy: x = v(0), y = t(1)
  k_gemm_nt<<<dim3(2, 2), 256, 0, stream>>>(Ac, Ac, AAt, SK, SK, NC);
  k_gemm_nt<<<dim3(2, 2), 256, 0, stream>>>(Bc, Ac, BAt, SK, SK, NC);
  k_mask<<<64, 256, 0, stream>>>(ev1, ev0, scal, Dm);
  k_cholsolve<<<SK, 128, 0, stream>>>(AAt, BAt, Dm, Msg, Cxy);
  // Cyx: x = t(1), y = v(0)
  k_gemm_nt<<<dim3(2, 2), 256, 0, stream>>>(Bc, Bc, AAt, SK, SK, NC);
  k_gemm_nt<<<dim3(2, 2), 256, 0, stream>>>(Ac, Bc, BAt, SK, SK, NC);
  k_mask<<<64, 256, 0, stream>>>(ev0, ev1, scal, Dm);
  k_cholsolve<<<SK, 128, 0, stream>>>(AAt, BAt, Dm, Msg, Cyx);

  // losses (deterministic partial-slot reduction)
  k_gemm_nn<<<dim3(2, 2), 256, 0, stream>>>(Cxy, Cyx, P1, SK, SK, SK);
  k_frob_iden<<<32, 256, 0, stream>>>(P1, lpart, 0);
  k_gemm_nn<<<dim3(2, 2), 256, 0, stream>>>(Cyx, Cxy, P1, SK, SK, SK);
  k_frob_iden<<<32, 256, 0, stream>>>(P1, lpart, 1);
  k_gemm_tn<<<dim3(2, 2), 256, 0, stream>>>(Cxy, Cxy, P1, SK, SK, SK);
  k_frob_iden<<<32, 256, 0, stream>>>(P1, lpart, 2);
  k_gemm_tn<<<dim3(2, 2), 256, 0, stream>>>(Cyx, Cyx, P1, SK, SK, SK);
  k_frob_iden<<<32, 256, 0, stream>>>(P1, lpart, 3);
  k_lap<<<32, 256, 0, stream>>>(Cxy, ev0, ev1, lpart, 4);
  k_lap<<<32, 256, 0, stream>>>(Cyx, ev1, ev0, lpart, 5);
  k_writeout<<<1, 64, 0, stream>>>(lpart, (float*)d_out);
}

// Round 3
// 719230.225 us; speedup vs baseline: 1.4171x; 1.4171x over previous
//
#include <hip/hip_runtime.h>
#include <hip/hip_cooperative_groups.h>
#include <math.h>

namespace cg = cooperative_groups;

#define NN 4096      // points
#define NC 768       // feature dim
#define KK 16        // knn k
#define SK 128       // spectral basis size
#define LM 1024      // Lanczos steps
#define LAMBDA_ 100.0f

typedef unsigned int u32;

__device__ __forceinline__ float hashf(u32 x) {
  x ^= x >> 16; x *= 0x7feb352dU; x ^= x >> 15; x *= 0x846ca68bU; x ^= x >> 16;
  return ((float)x) * (1.0f / 4294967296.0f);  // [0,1)
}

// ---------- row squared norms ----------
__global__ void k_sqnorm(const float* __restrict__ f, float* __restrict__ sq) {
  __shared__ float red[256];
  int i = blockIdx.x;
  float s = 0.f;
  for (int c = threadIdx.x; c < NC; c += 256) { float v = f[(size_t)i * NC + c]; s += v * v; }
  red[threadIdx.x] = s; __syncthreads();
  for (int o = 128; o > 0; o >>= 1) { if (threadIdx.x < o) red[threadIdx.x] += red[threadIdx.x + o]; __syncthreads(); }
  if (threadIdx.x == 0) sq[i] = red[0];
}

// ---------- d2 panel: pan[256][NN] for rows i0..i0+255 ----------
__global__ void __launch_bounds__(256) k_d2panel(const float* __restrict__ f, const float* __restrict__ sq,
                                                 float* __restrict__ pan, int i0) {
  __shared__ float As[16][65], Bs[16][65];
  int bj = blockIdx.x, bi = blockIdx.y;
  int row0 = i0 + bi * 64, col0 = bj * 64;
  int tx = threadIdx.x & 15, ty = threadIdx.x >> 4;
  float acc[4][4] = {};
  for (int k0 = 0; k0 < NC; k0 += 16) {
    for (int t2 = threadIdx.x; t2 < 1024; t2 += 256) {
      int kk = t2 & 15, rr = t2 >> 4;
      As[kk][rr] = f[(size_t)(row0 + rr) * NC + k0 + kk];
      Bs[kk][rr] = f[(size_t)(col0 + rr) * NC + k0 + kk];
    }
    __syncthreads();
#pragma unroll
    for (int kk = 0; kk < 16; kk++) {
      float av[4], bv[4];
#pragma unroll
      for (int a = 0; a < 4; a++) av[a] = As[kk][ty * 4 + a];
#pragma unroll
      for (int b = 0; b < 4; b++) bv[b] = Bs[kk][tx * 4 + b];
#pragma unroll
      for (int a = 0; a < 4; a++)
#pragma unroll
        for (int b = 0; b < 4; b++) acc[a][b] += av[a] * bv[b];
    }
    __syncthreads();
  }
#pragma unroll
  for (int a = 0; a < 4; a++) {
    int gr = row0 + ty * 4 + a;
    int pr = bi * 64 + ty * 4 + a;
    float sr = sq[gr];
#pragma unroll
    for (int b = 0; b < 4; b++) {
      int gc = col0 + tx * 4 + b;
      float v = sr + sq[gc] - 2.f * acc[a][b];
      v = fmaxf(v, 0.f);
      if (gr == gc) v += 1e10f;
      pan[(size_t)pr * NN + gc] = v;
    }
  }
}

// ---------- top-16 smallest per row ----------
__global__ void __launch_bounds__(256) k_topk(const float* __restrict__ pan, int i0,
                                              int* __restrict__ idx, float* __restrict__ dkv) {
  __shared__ float vals[NN];
  __shared__ float rv[256];
  __shared__ int ri[256];
  int r = blockIdx.x;
  const float* row = pan + (size_t)r * NN;
  for (int j = threadIdx.x; j < NN; j += 256) vals[j] = row[j];
  __syncthreads();
  for (int t3 = 0; t3 < KK; t3++) {
    float bv = 1e30f; int bi2 = NN;
    for (int j2 = threadIdx.x; j2 < NN; j2 += 256) {
      float v = vals[j2];
      if (v < bv || (v == bv && j2 < bi2)) { bv = v; bi2 = j2; }
    }
    rv[threadIdx.x] = bv; ri[threadIdx.x] = bi2;
    __syncthreads();
    for (int o = 128; o > 0; o >>= 1) {
      if (threadIdx.x < o) {
        float v2 = rv[threadIdx.x + o]; int i2 = ri[threadIdx.x + o];
        if (v2 < rv[threadIdx.x] || (v2 == rv[threadIdx.x] && i2 < ri[threadIdx.x])) {
          rv[threadIdx.x] = v2; ri[threadIdx.x] = i2;
        }
      }
      __syncthreads();
    }
    if (threadIdx.x == 0) {
      idx[(size_t)(i0 + r) * KK + t3] = ri[0];
      dkv[(size_t)(i0 + r) * KK + t3] = rv[0];
      vals[ri[0]] = 1e30f;
    }
    __syncthreads();
  }
}

// ---------- sigma2 = mean(dkv) + 1e-12 ----------
__global__ void k_partsum(const float* __restrict__ dkv, double* __restrict__ part) {
  __shared__ double red[256];
  double s = 0.0;
  for (int t2 = blockIdx.x * 256 + threadIdx.x; t2 < NN * KK; t2 += 64 * 256) s += (double)dkv[t2];
  red[threadIdx.x] = s; __syncthreads();
  for (int o = 128; o > 0; o >>= 1) { if (threadIdx.x < o) red[threadIdx.x] += red[threadIdx.x + o]; __syncthreads(); }
  if (threadIdx.x == 0) part[blockIdx.x] = red[0];
}
__global__ void k_sigma(const double* __restrict__ part, double* __restrict__ scal) {
  __shared__ double red[64];
  red[threadIdx.x] = part[threadIdx.x]; __syncthreads();
  for (int o = 32; o > 0; o >>= 1) { if (threadIdx.x < o) red[threadIdx.x] += red[threadIdx.x + o]; __syncthreads(); }
  if (threadIdx.x == 0) scal[0] = red[0] / (double)(NN * KK) + 1e-12;
}

// ---------- gaussian weights ----------
__global__ void k_wexp(const float* __restrict__ dkv, const double* __restrict__ scal,
                       float* __restrict__ wv) {
  int t = blockIdx.x * 256 + threadIdx.x;
  if (t >= NN * KK) return;
  float inv2s = (float)(0.5 / scal[0]);
  wv[t] = expf(-dkv[t] * inv2s);
}

// ---------- deterministic CSR transpose construction ----------
__global__ void k_count(const int* __restrict__ idx, int* __restrict__ cnt) {
  int t = blockIdx.x * 256 + threadIdx.x;
  if (t < NN * KK) atomicAdd(&cnt[idx[t]], 1);  // int atomics: order-invariant
}

__global__ void __launch_bounds__(1024) k_scan(const int* __restrict__ cnt,
                                               int* __restrict__ roff, int* __restrict__ rpos) {
  __shared__ int buf[1024];
  int t = threadIdx.x;
  int v[4]; int s = 0;
#pragma unroll
  for (int u = 0; u < 4; u++) { v[u] = cnt[t * 4 + u]; s += v[u]; }
  buf[t] = s; __syncthreads();
  for (int o = 1; o < 1024; o <<= 1) {
    int x = (t >= o) ? buf[t - o] : 0;
    __syncthreads();
    buf[t] += x;
    __syncthreads();
  }
  int run = (t == 0) ? 0 : buf[t - 1];
#pragma unroll
  for (int u = 0; u < 4; u++) { roff[t * 4 + u] = run; rpos[t * 4 + u] = run; run += v[u]; }
  if (t == 1023) roff[NN] = run;
}

__global__ void k_place(const int* __restrict__ idx, int* __restrict__ rpos, int* __restrict__ tsrc) {
  int i = blockIdx.x * 256 + threadIdx.x;
  if (i >= NN) return;
  for (int l = 0; l < KK; l++) {
    int j = idx[(size_t)i * KK + l];
    int e = atomicAdd(&rpos[j], 1);
    tsrc[e] = i * KK + l;
  }
}

__global__ void k_sortb(const int* __restrict__ roff, int* __restrict__ tsrc) {
  int i = blockIdx.x * 256 + threadIdx.x;
  if (i >= NN) return;
  int b = roff[i], e = roff[i + 1];
  for (int a = b + 1; a < e; a++) {
    int key = tsrc[a]; int c = a - 1;
    while (c >= b && tsrc[c] > key) { tsrc[c + 1] = tsrc[c]; c--; }
    tsrc[c + 1] = key;
  }
}

// ---------- degrees ----------
__global__ void k_deg(const float* __restrict__ wv, const int* __restrict__ roff,
                      const int* __restrict__ tsrc, float* __restrict__ deg) {
  int i = blockIdx.x * 256 + threadIdx.x;
  if (i >= NN) return;
  float s = 0.f;
  for (int l = 0; l < KK; l++) s += wv[(size_t)i * KK + l];
  float s2 = 0.f;
  for (int e = roff[i]; e < roff[i + 1]; e++) s2 += wv[tsrc[e]];
  deg[i] = 0.5f * (s + s2);
}

// ---------- normalized adjacency ----------
__global__ void k_wadj2(const float* __restrict__ wv, const int* __restrict__ idx,
                        const int* __restrict__ roff, const int* __restrict__ tsrc,
                        const float* __restrict__ deg,
                        float* __restrict__ wadjr, float* __restrict__ wadjt,
                        int* __restrict__ tcol) {
  int i = blockIdx.x * 256 + threadIdx.x;
  if (i >= NN) return;
  float di = 1.0f / sqrtf(deg[i] + 1e-8f);
  for (int l = 0; l < KK; l++) {
    int j = idx[(size_t)i * KK + l];
    float dj = 1.0f / sqrtf(deg[j] + 1e-8f);
    wadjr[(size_t)i * KK + l] = 0.5f * wv[(size_t)i * KK + l] * di * dj;
  }
  for (int e = roff[i]; e < roff[i + 1]; e++) {
    int s = tsrc[e];
    int sn = s / KK;
    float dj = 1.0f / sqrtf(deg[sn] + 1e-8f);
    wadjt[e] = 0.5f * wv[s] * di * dj;
    tcol[e] = sn;
  }
}

// ---------- fused cooperative Lanczos (full CGS2 reorthogonalization) ----------
// Grid: 256 blocks x 256 threads. Block b owns n-range [b*16, b*16+16).
// Per iteration: A) norm+q-write  B) SpMV  C/D) dots+update  E/F) dots+update
// 6 grid syncs per iteration. All reductions fixed-order -> deterministic.
__global__ void __launch_bounds__(256) k_lanczos(
    float* __restrict__ Q, float* __restrict__ y,
    const float* __restrict__ wadjr, const int* __restrict__ idx,
    const float* __restrict__ wadjt, const int* __restrict__ tcol,
    const int* __restrict__ roff,
    float* __restrict__ cvec, double* __restrict__ part,
    double* __restrict__ Ta, double* __restrict__ Tb, u32 seed) {
  cg::grid_group grid = cg::this_grid();
  const int b = blockIdx.x, t = threadIdx.x;
  const int n0 = b * 16;
  __shared__ double dred[256];
  __shared__ float fred[16][17];

  // init residual + norm partials
  if (t < 16) {
    int n = n0 + t;
    y[n] = hashf((u32)n * 2246822519u + seed) - 0.5f;
  }
  __syncthreads();
  if (t == 0) {
    double s = 0.0;
    for (int u = 0; u < 16; u++) { double v = (double)y[n0 + u]; s += v * v; }
    part[b] = s;
  }
  grid.sync();

  for (int it = 0; it < LM; it++) {
    // ---- Phase A: norm, beta, q = y/||y|| ----
    dred[t] = part[t];
    __syncthreads();
    for (int o = 128; o > 0; o >>= 1) { if (t < o) dred[t] += dred[t + o]; __syncthreads(); }
    double nrm = sqrt(dred[0]);
    if (b == 0 && t == 0 && it > 0) Tb[it - 1] = nrm;
    float inv = (float)(1.0 / (nrm > 1e-300 ? nrm : 1e-300));
    if (t < 16) {
      int n = n0 + t;
      Q[(size_t)it * NN + n] = y[n] * inv;
    }
    grid.sync();

    // ---- Phase B: SpMV y = M q_it (pure gather) ----
    {
      int gid = b * 256 + t;
      if (gid < NN) {
        const float* q = Q + (size_t)it * NN;
        float acc = 0.f;
#pragma unroll
        for (int l = 0; l < KK; l++) acc += wadjr[(size_t)gid * KK + l] * q[idx[(size_t)gid * KK + l]];
        for (int e = roff[gid]; e < roff[gid + 1]; e++) acc += wadjt[e] * q[tcol[e]];
        y[gid] = acc;
      }
    }
    grid.sync();

    // ---- CGS2: two (dots, update) passes ----
    for (int pass = 0; pass < 2; pass++) {
      // dots: block per j row
      for (int j = b; j <= it; j += 256) {
        const float* qj = Q + (size_t)j * NN;
        double s = 0.0;
        for (int n = t; n < NN; n += 256) s += (double)qj[n] * (double)y[n];
        dred[t] = s;
        __syncthreads();
        for (int o = 128; o > 0; o >>= 1) { if (t < o) dred[t] += dred[t + o]; __syncthreads(); }
        if (t == 0) {
          cvec[j] = (float)dred[0];
          if (pass == 0 && j == it) Ta[it] = dred[0];
        }
        __syncthreads();
      }
      grid.sync();
      // update: y[n0..n0+15] -= sum_j cvec[j] * Q[j][n]
      {
        int g = t >> 4, nn = n0 + (t & 15);
        float s = 0.f;
        for (int j = g; j <= it; j += 16) s += cvec[j] * Q[(size_t)j * NN + nn];
        fred[g][t & 15] = s;
        __syncthreads();
        for (int o = 8; o > 0; o >>= 1) {
          if (g < o) fred[g][t & 15] += fred[g + o][t & 15];
          __syncthreads();
        }
        if (t < 16) {
          int n = n0 + t;
          y[n] = y[n] - fred[0][t];
        }
        __syncthreads();
        if (pass == 1 && t == 0) {
          double s2 = 0.0;
          for (int u = 0; u < 16; u++) { double v = (double)y[n0 + u]; s2 += v * v; }
          part[b] = s2;
        }
      }
      grid.sync();
    }
  }
}

// ---------- bisection: top-SK eigenvalues of T ----------
__global__ void k_bisect(const double* __restrict__ Ta, const double* __restrict__ Tb,
                         double* __restrict__ theta, float* __restrict__ evL) {
  int j = threadIdx.x;
  if (j >= SK) return;
  int tgt = LM - j;
  double lo = -2.0, hi = 2.0;
  for (int iter = 0; iter < 60; iter++) {
    double mid = 0.5 * (lo + hi);
    int cnt = 0; double q = 1.0;
    for (int k = 0; k < LM; k++) {
      double off = (k > 0) ? Tb[k - 1] * Tb[k - 1] : 0.0;
      q = Ta[k] - mid - off / q;
      if (q < 0.0) cnt++;
      if (fabs(q) < 1e-280) q = -1e-280;
    }
    if (cnt >= tgt) hi = mid; else lo = mid;
  }
  theta[j] = 0.5 * (lo + hi);
  evL[j] = (float)(1.0 - theta[j]);
}

// ---------- inverse iteration for eigenvectors of T ----------
__global__ void k_invit(const double* __restrict__ Ta, const double* __restrict__ Tb,
                        const double* __restrict__ theta,
                        double* __restrict__ dws, double* __restrict__ ews,
                        double* __restrict__ fws, double* __restrict__ rws,
                        float* __restrict__ Ym) {
  int j = threadIdx.x;
  if (j >= SK) return;
  double sig = theta[j];
  for (int k = 0; k < LM; k++)
    rws[(size_t)k * SK + j] = (double)hashf((u32)k * 2654435761u + (u32)j * 40503u + 17u) - 0.5;
  for (int pass = 0; pass < 3; pass++) {
    double dk = Ta[0] - sig;
    double ek = Tb[0];
    double fk = 0.0;
    double rk = rws[j];
    for (int k = 0; k < LM - 1; k++) {
      double bk = Tb[k];
      double dn = Ta[k + 1] - sig;
      double en = (k + 2 < LM) ? Tb[k + 1] : 0.0;
      double rn = rws[(size_t)(k + 1) * SK + j];
      double dd, ee, ff, dk2, ek2, rkeep, rnext;
      if (fabs(dk) >= fabs(bk)) {
        double dsafe = (fabs(dk) > 1e-300) ? dk : 1e-300;
        double m = bk / dsafe;
        dd = dsafe; ee = ek; ff = fk;
        dk2 = dn - m * ek;
        ek2 = en - m * fk;
        rkeep = rk;
        rnext = rn - m * rk;
      } else {
        double m = dk / bk;
        dd = bk; ee = dn; ff = en;
        dk2 = ek - m * dn;
        ek2 = fk - m * en;
        rkeep = rn;
        rnext = rk - m * rn;
      }
      dws[(size_t)k * SK + j] = dd;
      ews[(size_t)k * SK + j] = ee;
      fws[(size_t)k * SK + j] = ff;
      rws[(size_t)k * SK + j] = rkeep;
      rk = rnext; dk = dk2; ek = ek2; fk = 0.0;
    }
    if (fabs(dk) < 1e-300) dk = 1e-300;
    dws[(size_t)(LM - 1) * SK + j] = dk;
    ews[(size_t)(LM - 1) * SK + j] = 0.0;
    fws[(size_t)(LM - 1) * SK + j] = 0.0;
    rws[(size_t)(LM - 1) * SK + j] = rk;
    double y1 = 0.0, y2 = 0.0, nr = 0.0;
    for (int k = LM - 1; k >= 0; k--) {
      double dv = dws[(size_t)k * SK + j];
      double yk = (rws[(size_t)k * SK + j] - ews[(size_t)k * SK + j] * y1 - fws[(size_t)k * SK + j] * y2) / dv;
      rws[(size_t)k * SK + j] = yk;
      y2 = y1; y1 = yk;
      nr += yk * yk;
    }
    double inv = 1.0 / sqrt(nr > 1e-300 ? nr : 1e-300);
    for (int k = 0; k < LM; k++) rws[(size_t)k * SK + j] *= inv;
  }
  for (int k = 0; k < LM; k++) Ym[(size_t)k * SK + j] = (float)rws[(size_t)k * SK + j];
}

// ---------- MGS on Ym columns ----------
__device__ __forceinline__ double wred64(double v) {
  for (int o = 32; o > 0; o >>= 1) v += __shfl_down(v, o, 64);
  return v;
}
__global__ void __launch_bounds__(256) k_mgsY(float* __restrict__ Ym) {
  __shared__ double lds[8];
  int t = threadIdx.x;
  for (int j = 0; j < SK; j++) {
    for (int jj = 0; jj < j; jj++) {
      double s = 0.0;
      for (int k = t; k < LM; k += 256) s += (double)Ym[(size_t)k * SK + jj] * (double)Ym[(size_t)k * SK + j];
      __syncthreads();
      s = wred64(s);
      if ((t & 63) == 0) lds[t >> 6] = s;
      __syncthreads();
      float cf = (float)(lds[0] + lds[1] + lds[2] + lds[3]);
      for (int k = t; k < LM; k += 256) Ym[(size_t)k * SK + j] -= cf * Ym[(size_t)k * SK + jj];
    }
    double s = 0.0;
    __syncthreads();
    for (int k = t; k < LM; k += 256) { double v = (double)Ym[(size_t)k * SK + j]; s += v * v; }
    s = wred64(s);
    if ((t & 63) == 0) lds[t >> 6] = s;
    __syncthreads();
    double nr = lds[0] + lds[1] + lds[2] + lds[3];
    float inv = (float)(1.0 / sqrt(nr > 1e-300 ? nr : 1e-300));
    for (int k = t; k < LM; k += 256) Ym[(size_t)k * SK + j] *= inv;
    __syncthreads();
  }
}

// ---------- generic tiled GEMMs ----------
__global__ void __launch_bounds__(256) k_gemm_tn(const float* __restrict__ A, const float* __restrict__ B,
                                                 float* __restrict__ Cm, int M, int P, int Kd) {
  __shared__ float As[16][65], Bs[16][65];
  int bm = blockIdx.x * 64, bp = blockIdx.y * 64;
  int tx = threadIdx.x & 15, ty = threadIdx.x >> 4;
  float acc[4][4] = {};
  for (int k0 = 0; k0 < Kd; k0 += 16) {
    for (int t2 = threadIdx.x; t2 < 1024; t2 += 256) {
      int mm = t2 & 63, kk = t2 >> 6;
      As[kk][mm] = A[(size_t)(k0 + kk) * M + bm + mm];
      Bs[kk][mm] = B[(size_t)(k0 + kk) * P + bp + mm];
    }
    __syncthreads();
#pragma unroll
    for (int kk = 0; kk < 16; kk++) {
      float av[4], bv[4];
#pragma unroll
      for (int a = 0; a < 4; a++) av[a] = As[kk][ty * 4 + a];
#pragma unroll
      for (int b = 0; b < 4; b++) bv[b] = Bs[kk][tx * 4 + b];
#pragma unroll
      for (int a = 0; a < 4; a++)
#pragma unroll
        for (int b = 0; b < 4; b++) acc[a][b] += av[a] * bv[b];
    }
    __syncthreads();
  }
#pragma unroll
  for (int a = 0; a < 4; a++)
#pragma unroll
    for (int b = 0; b < 4; b++)
      Cm[(size_t)(bm + ty * 4 + a) * P + bp + tx * 4 + b] = acc[a][b];
}

__global__ void __launch_bounds__(256) k_gemm_nt(const float* __restrict__ A, const float* __restrict__ B,
                                                 float* __restrict__ Cm, int M, int P, int Kd) {
  __shared__ float As[16][65], Bs[16][65];
  int bm = blockIdx.x * 64, bp = blockIdx.y * 64;
  int tx = threadIdx.x & 15, ty = threadIdx.x >> 4;
  float acc[4][4] = {};
  for (int k0 = 0; k0 < Kd; k0 += 16) {
    for (int t2 = threadIdx.x; t2 < 1024; t2 += 256) {
      int kk = t2 & 15, mm = t2 >> 4;
      As[kk][mm] = A[(size_t)(bm + mm) * Kd + k0 + kk];
      Bs[kk][mm] = B[(size_t)(bp + mm) * Kd + k0 + kk];
    }
    __syncthreads();
#pragma unroll
    for (int kk = 0; kk < 16; kk++) {
      float av[4], bv[4];
#pragma unroll
      for (int a = 0; a < 4; a++) av[a] = As[kk][ty * 4 + a];
#pragma unroll
      for (int b = 0; b < 4; b++) bv[b] = Bs[kk][tx * 4 + b];
#pragma unroll
      for (int a = 0; a < 4; a++)
#pragma unroll
        for (int b = 0; b < 4; b++) acc[a][b] += av[a] * bv[b];
    }
    __syncthreads();
  }
#pragma unroll
  for (int a = 0; a < 4; a++)
#pragma unroll
    for (int b = 0; b < 4; b++)
      Cm[(size_t)(bm + ty * 4 + a) * P + bp + tx * 4 + b] = acc[a][b];
}

__global__ void __launch_bounds__(256) k_gemm_nn(const float* __restrict__ A, const float* __restrict__ B,
                                                 float* __restrict__ Cm, int M, int P, int Kd) {
  __shared__ float As[16][65], Bs[16][65];
  int bm = blockIdx.x * 64, bp = blockIdx.y * 64;
  int tx = threadIdx.x & 15, ty = threadIdx.x >> 4;
  float acc[4][4] = {};
  for (int k0 = 0; k0 < Kd; k0 += 16) {
    for (int t2 = threadIdx.x; t2 < 1024; t2 += 256) {
      int kk = t2 & 15, mm = t2 >> 4;
      As[kk][mm] = A[(size_t)(bm + mm) * Kd + k0 + kk];
    }
    for (int t2 = threadIdx.x; t2 < 1024; t2 += 256) {
      int mm = t2 & 63, kk = t2 >> 6;
      Bs[kk][mm] = B[(size_t)(k0 + kk) * P + bp + mm];
    }
    __syncthreads();
#pragma unroll
    for (int kk = 0; kk < 16; kk++) {
      float av[4], bv[4];
#pragma unroll
      for (int a = 0; a < 4; a++) av[a] = As[kk][ty * 4 + a];
#pragma unroll
      for (int b = 0; b < 4; b++) bv[b] = Bs[kk][tx * 4 + b];
#pragma unroll
      for (int a = 0; a < 4; a++)
#pragma unroll
        for (int b = 0; b < 4; b++) acc[a][b] += av[a] * bv[b];
    }
    __syncthreads();
  }
#pragma unroll
  for (int a = 0; a < 4; a++)
#pragma unroll
    for (int b = 0; b < 4; b++)
      Cm[(size_t)(bm + ty * 4 + a) * P + bp + tx * 4 + b] = acc[a][b];
}

// ---------- s = max(max ev_a, max ev_b) ----------
__global__ void k_smax(const float* __restrict__ ea, const float* __restrict__ eb, double* __restrict__ scal) {
  __shared__ float red[128];
  int t = threadIdx.x;
  red[t] = fmaxf(ea[t], eb[t]);
  __syncthreads();
  for (int o = 64; o > 0; o >>= 1) { if (t < o) red[t] = fmaxf(red[t], red[t + o]); __syncthreads(); }
  if (t == 0) scal[1] = (double)red[0];
}

// ---------- resolvent mask ----------
__global__ void k_mask(const float* __restrict__ evr, const float* __restrict__ evc,
                       const double* __restrict__ scal, float* __restrict__ Dm) {
  int t = blockIdx.x * 256 + threadIdx.x;
  if (t >= SK * SK) return;
  int i = t / SK, j = t % SK;
  float s = (float)scal[1];
  float g1 = sqrtf(fmaxf(evc[j] / s, 0.f));
  float g2 = sqrtf(fmaxf(evr[i] / s, 0.f));
  float a2 = g2 * g2 + 1.f, a1 = g1 * g1 + 1.f;
  float re = g2 / a2 - g1 / a1;
  float im = 1.f / a2 - 1.f / a1;
  Dm[t] = re * re + im * im;
}

// ---------- per-row Cholesky solve ----------
__global__ void __launch_bounds__(128) k_cholsolve(const float* __restrict__ AAt, const float* __restrict__ BAt,
                                                   const float* __restrict__ Dm, float* __restrict__ Msg,
                                                   float* __restrict__ Cout) {
  __shared__ float xs[SK];
  int i = blockIdx.x;
  float* Ms = Msg + (size_t)i * SK * SK;
  for (int t2 = threadIdx.x; t2 < SK * SK; t2 += 128) {
    int r = t2 / SK, c2 = t2 % SK;
    float v = AAt[t2];
    if (r == c2) v += LAMBDA_ * Dm[(size_t)i * SK + r];
    Ms[t2] = v;
  }
  if (threadIdx.x < SK) xs[threadIdx.x] = BAt[(size_t)i * SK + threadIdx.x];
  __syncthreads();
  for (int k = 0; k < SK; k++) {
    if (threadIdx.x == 0) Ms[k * SK + k] = sqrtf(fmaxf(Ms[k * SK + k], 1e-20f));
    __syncthreads();
    float dk = Ms[k * SK + k];
    for (int r = k + 1 + threadIdx.x; r < SK; r += 128) Ms[r * SK + k] /= dk;
    __syncthreads();
    int rem = SK - k - 1;
    for (int t2 = threadIdx.x; t2 < rem * rem; t2 += 128) {
      int r = k + 1 + t2 / rem, c2 = k + 1 + t2 % rem;
      Ms[r * SK + c2] -= Ms[r * SK + k] * Ms[c2 * SK + k];
    }
    __syncthreads();
  }
  for (int k = 0; k < SK; k++) {
    if (threadIdx.x == 0) xs[k] /= Ms[k * SK + k];
    __syncthreads();
    float xv = xs[k];
    for (int r = k + 1 + threadIdx.x; r < SK; r += 128) xs[r] -= Ms[r * SK + k] * xv;
    __syncthreads();
  }
  for (int k = SK - 1; k >= 0; k--) {
    if (threadIdx.x == 0) xs[k] /= Ms[k * SK + k];
    __syncthreads();
    float xv = xs[k];
    for (int r = threadIdx.x; r < k; r += 128) xs[r] -= Ms[k * SK + r] * xv;
    __syncthreads();
  }
  for (int t2 = threadIdx.x; t2 < SK; t2 += 128) Cout[(size_t)i * SK + t2] = xs[t2];
}

// ---------- loss partials (deterministic) ----------
__global__ void k_frob_iden(const float* __restrict__ Mat, double* __restrict__ lpart, int slot) {
  __shared__ double red[256];
  double s = 0.0;
  for (int t2 = blockIdx.x * 256 + threadIdx.x; t2 < SK * SK; t2 += 32 * 256) {
    float v = Mat[t2] - ((t2 / SK == t2 % SK) ? 1.f : 0.f);
    s += (double)v * (double)v;
  }
  red[threadIdx.x] = s; __syncthreads();
  for (int o = 128; o > 0; o >>= 1) { if (threadIdx.x < o) red[threadIdx.x] += red[threadIdx.x + o]; __syncthreads(); }
  if (threadIdx.x == 0) lpart[slot * 32 + blockIdx.x] = red[0];
}
__global__ void k_lap(const float* __restrict__ Cm, const float* __restrict__ evc,
                      const float* __restrict__ evr, double* __restrict__ lpart, int slot) {
  __shared__ double red[256];
  double s = 0.0;
  for (int t2 = blockIdx.x * 256 + threadIdx.x; t2 < SK * SK; t2 += 32 * 256) {
    int i = t2 / SK, j = t2 % SK;
    float v = Cm[t2] * (evc[j] - evr[i]);
    s += (double)v * (double)v;
  }
  red[threadIdx.x] = s; __syncthreads();
  for (int o = 128; o > 0; o >>= 1) { if (threadIdx.x < o) red[threadIdx.x] += red[threadIdx.x + o]; __syncthreads(); }
  if (threadIdx.x == 0) lpart[slot * 32 + blockIdx.x] = red[0];
}
__global__ void k_writeout(const double* __restrict__ lpart, float* __restrict__ out) {
  if (threadIdx.x == 0) {
    double b = 0.0, o = 0.0, l = 0.0;
    for (int s = 0; s < 64; s++) b += lpart[s];
    for (int s = 64; s < 128; s++) o += lpart[s];
    for (int s = 128; s < 192; s++) l += lpart[s];
    out[0] = (float)b; out[1] = (float)o; out[2] = (float)l;
  }
}

extern "C" void kernel_launch(void* const* d_in, const int* in_sizes, int n_in,
                              void* d_out, int out_size, void* d_ws, size_t ws_size,
                              hipStream_t stream) {
  const float* feats[2] = {(const float*)d_in[0], (const float*)d_in[1]};
  char* p = (char*)d_ws;
  auto alloc = [&](size_t bytes) -> void* {
    char* r = p;
    p += (bytes + 255) & ~(size_t)255;
    return (void*)r;
  };
  float* pan   = (float*)alloc(sizeof(float) * 256 * NN);
  float* sq    = (float*)alloc(sizeof(float) * NN);
  int*   idx   = (int*)alloc(sizeof(int) * (size_t)NN * KK);
  float* dkv   = (float*)alloc(sizeof(float) * (size_t)NN * KK);
  float* wv    = (float*)alloc(sizeof(float) * (size_t)NN * KK);
  float* wadjr = (float*)alloc(sizeof(float) * (size_t)NN * KK);
  float* wadjt = (float*)alloc(sizeof(float) * (size_t)NN * KK);
  int*   cnt   = (int*)alloc(sizeof(int) * NN);
  int*   roff  = (int*)alloc(sizeof(int) * (NN + 1));
  int*   rpos  = (int*)alloc(sizeof(int) * NN);
  int*   tsrc  = (int*)alloc(sizeof(int) * (size_t)NN * KK);
  int*   tcol  = (int*)alloc(sizeof(int) * (size_t)NN * KK);
  float* deg   = (float*)alloc(sizeof(float) * NN);
  float* Q     = (float*)alloc(sizeof(float) * (size_t)LM * NN);
  float* yv    = (float*)alloc(sizeof(float) * NN);
  float* cv    = (float*)alloc(sizeof(float) * LM);
  double* part = (double*)alloc(sizeof(double) * 256);
  double* scal = (double*)alloc(sizeof(double) * 8);
  double* Ta   = (double*)alloc(sizeof(double) * LM);
  double* Tb   = (double*)alloc(sizeof(double) * LM);
  double* theta= (double*)alloc(sizeof(double) * SK);
  double* dws  = (double*)alloc(sizeof(double) * (size_t)LM * SK);
  double* ews  = (double*)alloc(sizeof(double) * (size_t)LM * SK);
  double* fws  = (double*)alloc(sizeof(double) * (size_t)LM * SK);
  double* rws  = (double*)alloc(sizeof(double) * (size_t)LM * SK);
  float* Ym    = (float*)alloc(sizeof(float) * (size_t)LM * SK);
  float* U0    = (float*)alloc(sizeof(float) * (size_t)NN * SK);
  float* U1    = (float*)alloc(sizeof(float) * (size_t)NN * SK);
  float* ev0   = (float*)alloc(sizeof(float) * SK);
  float* ev1   = (float*)alloc(sizeof(float) * SK);
  float* Ac    = (float*)alloc(sizeof(float) * (size_t)SK * NC);
  float* Bc    = (float*)alloc(sizeof(float) * (size_t)SK * NC);
  float* AAt   = (float*)alloc(sizeof(float) * SK * SK);
  float* BAt   = (float*)alloc(sizeof(float) * SK * SK);
  float* Dm    = (float*)alloc(sizeof(float) * SK * SK);
  float* Cxy   = (float*)alloc(sizeof(float) * SK * SK);
  float* Cyx   = (float*)alloc(sizeof(float) * SK * SK);
  float* P1    = (float*)alloc(sizeof(float) * SK * SK);
  float* Msg   = (float*)alloc(sizeof(float) * (size_t)SK * SK * SK);
  double* lpart= (double*)alloc(sizeof(double) * 192);

  float* Us[2] = {U0, U1};
  float* evs[2] = {ev0, ev1};

  for (int s2 = 0; s2 < 2; s2++) {
    const float* f = feats[s2];
    k_sqnorm<<<NN, 256, 0, stream>>>(f, sq);
    for (int p2 = 0; p2 < 16; p2++) {
      k_d2panel<<<dim3(64, 4), 256, 0, stream>>>(f, sq, pan, p2 * 256);
      k_topk<<<256, 256, 0, stream>>>(pan, p2 * 256, idx, dkv);
    }
    k_partsum<<<64, 256, 0, stream>>>(dkv, part);
    k_sigma<<<1, 64, 0, stream>>>(part, scal);
    k_wexp<<<NN * KK / 256, 256, 0, stream>>>(dkv, scal, wv);
    // deterministic CSR transpose
    hipMemsetAsync(cnt, 0, sizeof(int) * NN, stream);
    k_count<<<NN * KK / 256, 256, 0, stream>>>(idx, cnt);
    k_scan<<<1, 1024, 0, stream>>>(cnt, roff, rpos);
    k_place<<<16, 256, 0, stream>>>(idx, rpos, tsrc);
    k_sortb<<<16, 256, 0, stream>>>(roff, tsrc);
    k_deg<<<16, 256, 0, stream>>>(wv, roff, tsrc, deg);
    k_wadj2<<<16, 256, 0, stream>>>(wv, idx, roff, tsrc, deg, wadjr, wadjt, tcol);
    // fused cooperative Lanczos (full CGS2)
    {
      u32 seed = 1234567u + (u32)s2 * 77777u;
      void* args[] = {(void*)&Q, (void*)&yv, (void*)&wadjr, (void*)&idx,
                      (void*)&wadjt, (void*)&tcol, (void*)&roff,
                      (void*)&cv, (void*)&part, (void*)&Ta, (void*)&Tb, (void*)&seed};
      hipLaunchCooperativeKernel((const void*)k_lanczos, dim3(256), dim3(256), args, 0, stream);
    }
    k_bisect<<<1, 128, 0, stream>>>(Ta, Tb, theta, evs[s2]);
    k_invit<<<1, 128, 0, stream>>>(Ta, Tb, theta, dws, ews, fws, rws, Ym);
    k_mgsY<<<1, 256, 0, stream>>>(Ym);
    k_gemm_tn<<<dim3(NN / 64, SK / 64), 256, 0, stream>>>(Q, Ym, Us[s2], NN, SK, LM);
  }

  // spectral coefficients
  k_gemm_tn<<<dim3(SK / 64, NC / 64), 256, 0, stream>>>(U0, feats[0], Ac, SK, NC, NN);
  k_gemm_tn<<<dim3(SK / 64, NC / 64), 256, 0, stream>>>(U1, feats[1], Bc, SK, NC, NN);
  k_smax<<<1, 128, 0, stream>>>(ev0, ev1, scal);

  // Cxy: x = v(0), y = t(1)
  k_gemm_nt<<<dim3(2, 2), 256, 0, stream>>>(Ac, Ac, AAt, SK, SK, NC);
  k_gemm_nt<<<dim3(2, 2), 256, 0, stream>>>(Bc, Ac, BAt, SK, SK, NC);
  k_mask<<<64, 256, 0, stream>>>(ev1, ev0, scal, Dm);
  k_cholsolve<<<SK, 128, 0, stream>>>(AAt, BAt, Dm, Msg, Cxy);
  // Cyx: x = t(1), y = v(0)
  k_gemm_nt<<<dim3(2, 2), 256, 0, stream>>>(Bc, Bc, AAt, SK, SK, NC);
  k_gemm_nt<<<dim3(2, 2), 256, 0, stream>>>(Ac, Bc, BAt, SK, SK, NC);
  k_mask<<<64, 256, 0, stream>>>(ev0, ev1, scal, Dm);
  k_cholsolve<<<SK, 128, 0, stream>>>(AAt, BAt, Dm, Msg, Cyx);

  // losses
  k_gemm_nn<<<dim3(2, 2), 256, 0, stream>>>(Cxy, Cyx, P1, SK, SK, SK);
  k_frob_iden<<<32, 256, 0, stream>>>(P1, lpart, 0);
  k_gemm_nn<<<dim3(2, 2), 256, 0, stream>>>(Cyx, Cxy, P1, SK, SK, SK);
  k_frob_iden<<<32, 256, 0, stream>>>(P1, lpart, 1);
  k_gemm_tn<<<dim3(2, 2), 256, 0, stream>>>(Cxy, Cxy, P1, SK, SK, SK);
  k_frob_iden<<<32, 256, 0, stream>>>(P1, lpart, 2);
  k_gemm_tn<<<dim3(2, 2), 256, 0, stream>>>(Cyx, Cyx, P1, SK, SK, SK);
  k_frob_iden<<<32, 256, 0, stream>>>(P1, lpart, 3);
  k_lap<<<32, 256, 0, stream>>>(Cxy, ev0, ev1, lpart, 4);
  k_lap<<<32, 256, 0, stream>>>(Cyx, ev1, ev0, lpart, 5);
  k_writeout<<<1, 64, 0, stream>>>(lpart, (float*)d_out);
}